// Round 1
// baseline (303.755 us; speedup 1.0000x reference)
//
#include <hip/hip_runtime.h>
#include <hip/hip_bf16.h>

#define A_DIM 1024
#define B_DIM 16
#define DM    512
#define NH    8
#define HD    64

#define LDT 72   // padded LDS leading dim (shorts); 144 B rows (16B-aligned)

typedef short s16x8 __attribute__((ext_vector_type(8)));   // 8 bf16, MFMA A/B frag
typedef short s16x4 __attribute__((ext_vector_type(4)));   // 4 bf16 (one tr-read result)
typedef float f32x4 __attribute__((ext_vector_type(4)));   // MFMA C/D frag

static __device__ __forceinline__ unsigned short f2b(float f) {
    __hip_bfloat16 h = __float2bfloat16(f);
    unsigned short u;
    __builtin_memcpy(&u, &h, 2);
    return u;
}
// packed f32x4 -> bf16x4 (two v_cvt_pk_bf16)
static __device__ __forceinline__ uint2 cvt4(float4 v) {
    __hip_bfloat162 lo = __float22bfloat162_rn(make_float2(v.x, v.y));
    __hip_bfloat162 hi = __float22bfloat162_rn(make_float2(v.z, v.w));
    unsigned int ulo, uhi;
    __builtin_memcpy(&ulo, &lo, 4);
    __builtin_memcpy(&uhi, &hi, 4);
    return make_uint2(ulo, uhi);
}

// ---------------------------------------------------------------------------
// Kernel 1: fused QKV projection.  C[t][o] = sum_k src[t][k] * W[o][k] + b[o]
// f32 inputs -> bf16 LDS staging -> bf16 MFMA.  Q,K,V all to [B][NH][A][HD]
// (coalesced d-contiguous stores).  Q is pre-scaled by HD^-0.5.
// ---------------------------------------------------------------------------
__global__ __launch_bounds__(256) void qkv_gemm(
    const float* __restrict__ src,
    const float* __restrict__ Wq, const float* __restrict__ bq,
    const float* __restrict__ Wk, const float* __restrict__ bk,
    const float* __restrict__ Wv, const float* __restrict__ bv,
    short* __restrict__ Qb, short* __restrict__ Kb, short* __restrict__ Vb)
{
    __shared__ short As[128 * LDT];
    __shared__ short Bs[128 * LDT];

    const int tid  = threadIdx.x;
    const int wave = tid >> 6, lane = tid & 63;
    const int quad = lane >> 4, l16 = lane & 15;
    const int waveM = (wave >> 1) * 64, waveN = (wave & 1) * 64;
    const int mbase = blockIdx.y * 128;
    const int nbase = blockIdx.x * 128;          // 0..1535
    const int mat   = nbase >> 9;                // 0:Q 1:K 2:V
    const float* W    = (mat == 0) ? Wq : (mat == 1) ? Wk : Wv;
    const float* bvec = (mat == 0) ? bq : (mat == 1) ? bk : bv;
    short* dst        = (mat == 0) ? Qb : (mat == 1) ? Kb : Vb;
    const float oscale = (mat == 0) ? 0.125f : 1.0f;   // fold HD^-0.5 into Q
    const int wrow0 = nbase & 511;

    f32x4 acc[4][4];
    #pragma unroll
    for (int i = 0; i < 4; i++)
        #pragma unroll
        for (int j = 0; j < 4; j++)
            acc[i][j] = (f32x4){0.f, 0.f, 0.f, 0.f};

    for (int kb = 0; kb < 8; ++kb) {
        __syncthreads();
        #pragma unroll
        for (int p = 0; p < 8; p++) {
            int chunk = tid + p * 256;
            int row = chunk >> 4, c = chunk & 15;
            float4 a4 = *(const float4*)&src[(mbase + row) * 512 + kb * 64 + c * 4];
            *(uint2*)&As[row * LDT + c * 4] = cvt4(a4);
            float4 w4 = *(const float4*)&W[(wrow0 + row) * 512 + kb * 64 + c * 4];
            *(uint2*)&Bs[row * LDT + c * 4] = cvt4(w4);
        }
        __syncthreads();
        #pragma unroll
        for (int k0i = 0; k0i < 2; k0i++) {
            s16x8 af[4], bf[4];
            #pragma unroll
            for (int mi = 0; mi < 4; mi++)
                af[mi] = *(const s16x8*)&As[(waveM + mi * 16 + l16) * LDT + (k0i * 4 + quad) * 8];
            #pragma unroll
            for (int ni = 0; ni < 4; ni++)
                bf[ni] = *(const s16x8*)&Bs[(waveN + ni * 16 + l16) * LDT + (k0i * 4 + quad) * 8];
            #pragma unroll
            for (int mi = 0; mi < 4; mi++)
                #pragma unroll
                for (int ni = 0; ni < 4; ni++)
                    acc[mi][ni] = __builtin_amdgcn_mfma_f32_16x16x32_bf16(
                        af[mi], bf[ni], acc[mi][ni], 0, 0, 0);
        }
    }

    // epilogue: C/D layout col=l16 (n), row=quad*4+r (m); scatter to [B][NH][A][HD]
    #pragma unroll
    for (int mi = 0; mi < 4; mi++) {
        #pragma unroll
        for (int ni = 0; ni < 4; ni++) {
            #pragma unroll
            for (int r = 0; r < 4; r++) {
                int t = mbase + waveM + mi * 16 + quad * 4 + r;       // token = a*16+b
                int o = wrow0 + waveN + ni * 16 + l16;                // col in [0,512)
                float v = (acc[mi][ni][r] + bvec[o]) * oscale;
                int a = t >> 4, bb = t & 15, n = o >> 6, d = o & 63;
                dst[((bb * NH + n) * A_DIM + a) * HD + d] = (short)f2b(v);
            }
        }
    }
}

// ---------------------------------------------------------------------------
// Kernel 2: flash attention over asset dim.  One wg per (b*nh, 64-row q-tile).
// Q (pre-scaled), K, V bf16 [bn][a][d]; bias f32.
// Fixed-max softmax: P = exp(s+bias); l accumulated per-lane, reduced once.
//
// v2 changes vs previous kernel (VALU/LDS-op-bound per rocprof):
//  - V staged in a 4x16-subtiled LDS layout with b128 writes; PV B-frags read
//    with ds_read_b64_tr_b16 (HW transpose) -> kills the 16 scalar ds_write_b16
//    per lane-iter software transpose.
//  - P stored transposed (Pt[k][q], same subtiling): 4 x ds_write_b64 with
//    packed cvt_pk instead of 16 scalar converts + 16 scalar ds_write_b16;
//    PV A-frags also via tr-read.
//  - T14 async staging: next K/V tile prefetched into regs at compute start,
//    written to LDS after the next barrier (global latency hidden).
// ---------------------------------------------------------------------------
__global__ __launch_bounds__(256) void attn_kernel(
    const short* __restrict__ Qb, const short* __restrict__ Kb,
    const short* __restrict__ Vb, const float* __restrict__ bias,
    short* __restrict__ AO)
{
    __shared__ __align__(16) short Ks[64 * LDT];        // K tile, row-major padded
    __shared__ __align__(16) short Vsub[64 * 64];       // V tile, subtiled [d/16][k/4][4][16]
    __shared__ __align__(16) short Pts[4][64 * 16];     // per-wave P^T, subtiled [k/4][4][16]

    const int tid  = threadIdx.x;
    const int wave = tid >> 6, lane = tid & 63;
    const int quad = lane >> 4, l16 = lane & 15;
    const int bn = blockIdx.y;                       // b*8 + n
    const int qrow0 = blockIdx.x * 64 + wave * 16;   // this wave's first q row

    const short* Qg = Qb + bn * (A_DIM * HD);
    const short* Kg = Kb + bn * (A_DIM * HD);
    const short* Vg = Vb + bn * (A_DIM * HD);

    // Q fragments in registers: A[m=l16][k=k0i*32+quad*8+j]
    s16x8 qf[2];
    #pragma unroll
    for (int k0i = 0; k0i < 2; k0i++)
        qf[k0i] = *(const s16x8*)&Qg[(qrow0 + l16) * HD + k0i * 32 + quad * 8];

    // staging geometry: thread -> (row = srow + p*32, col group sc), 8 bf16 each
    const int srow = tid >> 3, sc = tid & 7;          // srow 0..31, sc 0..7
    const short* kld = Kg + srow * HD + sc * 8;
    const short* vld = Vg + srow * HD + sc * 8;

    // tr-read per-lane base byte offsets into LDS.
    //  subtile (4 k-rows x 16 cols) = 128 B; lane supplies subtile_base + l16*8;
    //  HW delivers column l16 of the 4x16 block; quad's k-subtile = +quad*256 B
    //  (2 subtiles per quad; second 4 k-rows via offset:128).
    const unsigned lane_tr = (unsigned)(quad * 256 + l16 * 8);
    const unsigned pt_addr = (unsigned)(unsigned long long)&Pts[wave][0] + lane_tr;
    const unsigned vt_addr = (unsigned)(unsigned long long)&Vsub[0]     + lane_tr;

    float lsum[4];
    f32x4 of[4];
    #pragma unroll
    for (int r = 0; r < 4; r++) lsum[r] = 0.f;
    #pragma unroll
    for (int db = 0; db < 4; db++) of[db] = (f32x4){0.f, 0.f, 0.f, 0.f};

    // prologue: prefetch tile kb=0 into registers
    s16x8 kpre[2], vpre[2];
    #pragma unroll
    for (int p = 0; p < 2; p++) {
        kpre[p] = *(const s16x8*)&kld[p * 32 * HD];
        vpre[p] = *(const s16x8*)&vld[p * 32 * HD];
    }

    for (int kb = 0; kb < 16; ++kb) {
        __syncthreads();   // all waves done reading previous K/V tiles
        #pragma unroll
        for (int p = 0; p < 2; p++) {
            int row = srow + p * 32;                     // key idx in tile
            *(s16x8*)&Ks[row * LDT + sc * 8] = kpre[p];
            // V subtiled: elem (k=row, d=sc*8+j) ->
            //   subtile (ds=sc>>1, ks=row>>2), pos (row&3, (sc&1)*8+j)  [contiguous]
            *(s16x8*)&Vsub[(((sc >> 1) * 16 + (row >> 2)) * 64)
                           + (row & 3) * 16 + (sc & 1) * 8] = vpre[p];
        }
        __syncthreads();

        // T14: issue next tile's global loads now; latency hides under compute
        if (kb < 15) {
            #pragma unroll
            for (int p = 0; p < 2; p++) {
                kpre[p] = *(const s16x8*)&kld[((kb + 1) * 64 + p * 32) * HD];
                vpre[p] = *(const s16x8*)&vld[((kb + 1) * 64 + p * 32) * HD];
            }
        }

        // S = Q K^T (+bias folded into exp arg)   C-layout: col=l16, row=quad*4+r
        float sv[4][4];
        #pragma unroll
        for (int cb = 0; cb < 4; cb++) {
            f32x4 s = (f32x4){0.f, 0.f, 0.f, 0.f};
            #pragma unroll
            for (int k0i = 0; k0i < 2; k0i++) {
                s16x8 kf = *(const s16x8*)&Ks[(cb * 16 + l16) * LDT + (k0i * 4 + quad) * 8];
                s = __builtin_amdgcn_mfma_f32_16x16x32_bf16(qf[k0i], kf, s, 0, 0, 0);
            }
            #pragma unroll
            for (int r = 0; r < 4; r++) {
                int arow = qrow0 + quad * 4 + r;
                int kcol = kb * 64 + cb * 16 + l16;
                sv[cb][r] = s[r] + bias[arow * A_DIM + kcol];
            }
        }

        // P = exp(s)  (fixed max: logits are O(6), safe in f32/bf16)
        // Pack 4 rows (r=0..3 -> q=quad*4+r, contiguous in Pt) per b64 write.
        #pragma unroll
        for (int cb = 0; cb < 4; cb++) {
            float p0 = __expf(sv[cb][0]);
            float p1 = __expf(sv[cb][1]);
            float p2 = __expf(sv[cb][2]);
            float p3 = __expf(sv[cb][3]);
            lsum[0] += p0; lsum[1] += p1; lsum[2] += p2; lsum[3] += p3;
            // Pt elem (k=cb*16+l16, q=quad*4+r): subtile ks=cb*4+(l16>>2),
            // pos (l16&3, quad*4+r)
            *(uint2*)&Pts[wave][(cb * 4 + (l16 >> 2)) * 64
                                + (l16 & 3) * 16 + quad * 4] =
                cvt4(make_float4(p0, p1, p2, p3));
        }

        // ensure Pt writes (and V staging) are committed before tr reads
        asm volatile("s_waitcnt lgkmcnt(0)" ::: "memory");

        // O += P @ V via HW transpose reads.
        //  A-frag: P[q=l16][k=k0i*32+quad*8+j]  from Pt subtiles
        //  B-frag: V[k=k0i*32+quad*8+j][d=db*16+l16] from Vsub subtiles
        s16x4 pl[2], ph[2], vl[2][4], vh[2][4];
        #pragma unroll
        for (int k0i = 0; k0i < 2; k0i++) {
            asm volatile("ds_read_b64_tr_b16 %0, %2\n\t"
                         "ds_read_b64_tr_b16 %1, %2 offset:128"
                         : "=&v"(pl[k0i]), "=&v"(ph[k0i])
                         : "v"(pt_addr + (unsigned)(k0i * 1024)));
            #pragma unroll
            for (int db = 0; db < 4; db++)
                asm volatile("ds_read_b64_tr_b16 %0, %2\n\t"
                             "ds_read_b64_tr_b16 %1, %2 offset:128"
                             : "=&v"(vl[k0i][db]), "=&v"(vh[k0i][db])
                             : "v"(vt_addr + (unsigned)(db * 2048 + k0i * 1024)));
        }
        asm volatile("s_waitcnt lgkmcnt(0)" ::: "memory");
        __builtin_amdgcn_sched_barrier(0);   // keep MFMA below the wait (rule #18)

        #pragma unroll
        for (int k0i = 0; k0i < 2; k0i++) {
            s16x8 pf = __builtin_shufflevector(pl[k0i], ph[k0i],
                                               0, 1, 2, 3, 4, 5, 6, 7);
            #pragma unroll
            for (int db = 0; db < 4; db++) {
                s16x8 vf = __builtin_shufflevector(vl[k0i][db], vh[k0i][db],
                                                   0, 1, 2, 3, 4, 5, 6, 7);
                of[db] = __builtin_amdgcn_mfma_f32_16x16x32_bf16(pf, vf, of[db], 0, 0, 0);
            }
        }
    }

    // reduce l across the 16 lanes sharing each row (once, not per-iter)
    #pragma unroll
    for (int r = 0; r < 4; r++) {
        float ps = lsum[r];
        ps += __shfl_xor(ps, 1);
        ps += __shfl_xor(ps, 2);
        ps += __shfl_xor(ps, 4);
        ps += __shfl_xor(ps, 8);
        lsum[r] = 1.0f / ps;
    }

    // epilogue: [A][B][DM] token layout (bf16)
    const int b = bn >> 3, n = bn & 7;
    #pragma unroll
    for (int db = 0; db < 4; db++) {
        #pragma unroll
        for (int r = 0; r < 4; r++) {
            int a = qrow0 + quad * 4 + r;
            int d = db * 16 + l16;
            float v = of[db][r] * lsum[r];
            AO[(a * B_DIM + b) * DM + n * HD + d] = (short)f2b(v);
        }
    }
}

// ---------------------------------------------------------------------------
// Kernel 3: output projection.  out[t][o] = sum_k X[t][k] * Wo[o][k] + bo[o]
// X bf16 (attention output); Wo/bo f32; out f32.
// ---------------------------------------------------------------------------
__global__ __launch_bounds__(256) void out_gemm(
    const short* __restrict__ Xin,
    const float* __restrict__ Wo, const float* __restrict__ bo,
    float* __restrict__ out)
{
    __shared__ short As[128 * LDT];
    __shared__ short Bs[128 * LDT];

    const int tid  = threadIdx.x;
    const int wave = tid >> 6, lane = tid & 63;
    const int quad = lane >> 4, l16 = lane & 15;
    const int waveM = (wave >> 1) * 64, waveN = (wave & 1) * 64;
    const int mbase = blockIdx.y * 128;
    const int nbase = blockIdx.x * 128;   // 0..511

    f32x4 acc[4][4];
    #pragma unroll
    for (int i = 0; i < 4; i++)
        #pragma unroll
        for (int j = 0; j < 4; j++)
            acc[i][j] = (f32x4){0.f, 0.f, 0.f, 0.f};

    for (int kb = 0; kb < 8; ++kb) {
        __syncthreads();
        #pragma unroll
        for (int p = 0; p < 4; p++) {
            int chunk = tid + p * 256;
            int row = chunk >> 3, c = chunk & 7;
            *(s16x8*)&As[row * LDT + c * 8] =
                *(const s16x8*)&Xin[(mbase + row) * 512 + kb * 64 + c * 8];
        }
        #pragma unroll
        for (int p = 0; p < 8; p++) {
            int chunk = tid + p * 256;
            int row = chunk >> 4, c = chunk & 15;
            float4 w4 = *(const float4*)&Wo[(nbase + row) * 512 + kb * 64 + c * 4];
            *(uint2*)&Bs[row * LDT + c * 4] = cvt4(w4);
        }
        __syncthreads();
        #pragma unroll
        for (int k0i = 0; k0i < 2; k0i++) {
            s16x8 af[4], bf[4];
            #pragma unroll
            for (int mi = 0; mi < 4; mi++)
                af[mi] = *(const s16x8*)&As[(waveM + mi * 16 + l16) * LDT + (k0i * 4 + quad) * 8];
            #pragma unroll
            for (int ni = 0; ni < 4; ni++)
                bf[ni] = *(const s16x8*)&Bs[(waveN + ni * 16 + l16) * LDT + (k0i * 4 + quad) * 8];
            #pragma unroll
            for (int mi = 0; mi < 4; mi++)
                #pragma unroll
                for (int ni = 0; ni < 4; ni++)
                    acc[mi][ni] = __builtin_amdgcn_mfma_f32_16x16x32_bf16(
                        af[mi], bf[ni], acc[mi][ni], 0, 0, 0);
        }
    }

    #pragma unroll
    for (int mi = 0; mi < 4; mi++) {
        #pragma unroll
        for (int ni = 0; ni < 4; ni++) {
            #pragma unroll
            for (int r = 0; r < 4; r++) {
                int t = mbase + waveM + mi * 16 + quad * 4 + r;
                int o = nbase + waveN + ni * 16 + l16;
                out[t * 512 + o] = acc[mi][ni][r] + bo[o];
            }
        }
    }
}

// ---------------------------------------------------------------------------
extern "C" void kernel_launch(void* const* d_in, const int* in_sizes, int n_in,
                              void* d_out, int out_size, void* d_ws, size_t ws_size,
                              hipStream_t stream) {
    const float* src  = (const float*)d_in[0];
    const float* bias = (const float*)d_in[1];
    const float* Wq   = (const float*)d_in[2];
    const float* bq   = (const float*)d_in[3];
    const float* Wk   = (const float*)d_in[4];
    const float* bk   = (const float*)d_in[5];
    const float* Wv   = (const float*)d_in[6];
    const float* bv   = (const float*)d_in[7];
    const float* Wo   = (const float*)d_in[8];
    const float* bo   = (const float*)d_in[9];

    short* ws = (short*)d_ws;
    short* Qb = ws;                        // [B][NH][A][HD] bf16, 16 MB (Q pre-scaled)
    short* Kb = ws + (size_t)(1 << 23);    // 16 MB
    short* Vb = ws + (size_t)(2 << 23);    // 16 MB

    const bool big_ws = ws_size >= (size_t)(64u << 20);
    short* AO = big_ws ? (ws + (size_t)3 * (1 << 23))   // 4th ws region, 16 MB
                       : (short*)d_out;                 // fallback: stage in d_out

    qkv_gemm<<<dim3(12, 128), 256, 0, stream>>>(src, Wq, bq, Wk, bk, Wv, bv, Qb, Kb, Vb);
    attn_kernel<<<dim3(16, 128), 256, 0, stream>>>(Qb, Kb, Vb, bias, AO);

    if (big_ws) {
        out_gemm<<<dim3(4, 128), 256, 0, stream>>>(AO, Wo, bo, (float*)d_out);
    } else {
        float* Cs = (float*)d_ws;          // over dead Q+K regions (32 MB)
        out_gemm<<<dim3(4, 128), 256, 0, stream>>>(AO, Wo, bo, Cs);
        (void)hipMemcpyAsync(d_out, Cs, (size_t)out_size * sizeof(float),
                             hipMemcpyDeviceToDevice, stream);
    }
}